// Round 13
// baseline (7606.223 us; speedup 1.0000x reference)
//
#include <hip/hip_runtime.h>
#include <hip/hip_bf16.h>

// ---------------------------------------------------------------------------
// UnifiedModelRNN: B=256,S=512,I=64,H=256. 16 blocks x 512 threads (8 waves,
// 2/SIMD); block g owns batch rows [16g,16g+16). No grid sync.
// R13 = R12 but every global_load_lds uses offset=0 with exact per-op
// pointers (the R8-proven mechanics). R10-R12 all used the builtin's imm
// offset arg (undocumented semantics on gfx950 FLAT-LDS) and all failed;
// R8 with offset=0 passed. Everything else as R12:
//  * Per-wave consume-order stream (88 frags x 1KB): [h0(4) h1(4)]
//    [kt2..kt9, kt0, kt1 x 8 frags]. h = pit_w1 (w<4) / time_w1 (w>=4).
//  * 12 chunks/step, 2-slot ring (8x2x8KB), ONE chunk in flight:
//    consume c (counted vmcnt) -> MFMAs -> lgkmcnt(0) -> issue c+2.
//  * sched_barrier(0) pinning; lgkm-only barriers; ar weights in regs.
// ---------------------------------------------------------------------------

typedef float f32x4 __attribute__((ext_vector_type(4)));
typedef short s16x8 __attribute__((ext_vector_type(8)));

#define S_LEN 512
#define I_DIM 64
#define NT    512

// ws element offsets (unsigned short = bf16)
#define WS_G2    0        // 8 waves x 88 frags x 512 elems (consume order)
#define WS_AXF   360448   // ar_w1[:, 2:66]: 8 frags
#define WS_A2F   364544   // ar_w2: 8 frags
#define WS_TOTAL 368640
#define WSTRIDE  90112    // bytes per wave stream (88 KB)

#define OUT_PIT  0
#define OUT_TIME 131072
#define OUT_AR   262144

#define ALD 328
#define XLD 72

#define SBAR() __builtin_amdgcn_sched_barrier(0)

__device__ __forceinline__ float sigf(float x) {
  return 1.0f / (1.0f + __expf(-x));
}
__device__ __forceinline__ float tanh_fast(float x) {
  float c = fminf(fmaxf(x, -15.0f), 15.0f);
  float e = __expf(2.0f * c);
  return (e - 1.0f) / (e + 1.0f);
}
__device__ __forceinline__ unsigned short f2bf(float f) {
  __hip_bfloat16 h = __float2bfloat16(f);
  return *reinterpret_cast<unsigned short*>(&h);
}
// LDS-only barrier: does NOT drain vmcnt -> DMA stays in flight.
__device__ __forceinline__ void sync_lds() {
  asm volatile("s_waitcnt lgkmcnt(0)" ::: "memory");
  SBAR();
  __builtin_amdgcn_s_barrier();
  SBAR();
}
// 16B/lane global->LDS DMA, offset=0, exact pointers (R8-proven form).
__device__ __forceinline__ void gld16(const char* g, unsigned short* l) {
  __builtin_amdgcn_global_load_lds(
      (const __attribute__((address_space(1))) unsigned int*)g,
      (__attribute__((address_space(3))) unsigned int*)l, 16, 0, 0);
}

__global__ void prep_kernel(const float* __restrict__ w_ih,
                            const float* __restrict__ w_hh,
                            const float* __restrict__ pit_w1,
                            const float* __restrict__ time_w1,
                            const float* __restrict__ ar_w1,
                            const float* __restrict__ ar_w2,
                            unsigned short* __restrict__ ws) {
  int idx = blockIdx.x * 256 + threadIdx.x;
  if (idx >= WS_TOTAL) return;
  int lane = (idx >> 3) & 63;
  int e    = idx & 7;
  int lrow = lane & 15, lgrp = lane >> 4;
  float v;
  if (idx < WS_AXF) {
    int F = idx >> 9;          // 0..703
    int w = F / 88;
    int p = F - 88 * w;        // stream position
    if (p < 8) {               // head frag: pit (w<4) / time (w>=4)
      int row = (w & 3) * 16 + lrow;
      int col = p * 32 + lgrp * 8 + e;
      v = (w < 4) ? pit_w1[row * 256 + col] : time_w1[row * 257 + col];
    } else {                   // gate frag
      int pp = p - 8;          // 0..79
      int ktidx = pp >> 3, qm = pp & 7;
      int kt = (ktidx < 8) ? ktidx + 2 : ktidx - 8;  // kt2..kt9,kt0,kt1
      int q = qm >> 1, m = qm & 1;
      int row = q * 256 + w * 32 + m * 16 + lrow;
      int col = kt * 32 + lgrp * 8 + e;
      v = (col < I_DIM) ? w_ih[row * I_DIM + col] : w_hh[row * 256 + col - I_DIM];
    }
  } else if (idx < WS_A2F) {
    int f = (idx - WS_AXF) >> 9;     // wv*2+kt
    int wv = f >> 1, kt = f & 1;
    v = ar_w1[(wv * 16 + lrow) * 66 + 2 + kt * 32 + lgrp * 8 + e];
  } else {
    int f = (idx - WS_A2F) >> 9;
    int wv = f >> 1, kt = f & 1;
    v = ar_w2[(wv * 16 + lrow) * 64 + kt * 32 + lgrp * 8 + e];
  }
  ws[idx] = f2bf(v);
}

#define AFRAG(kt) (*(const s16x8*)&A_lds[lrow][(kt) * 32 + 8 * lgrp])

// Head half-chunk: 4 frags (4KB), 4 ops, exact pointers, offset=0.
#define DMA4H(cbyte, slot)                                                     \
  do {                                                                         \
    SBAR();                                                                    \
    const char* g_ = wbase8 + (cbyte);                                         \
    gld16(g_,        &stg[wave][slot][0]);                                     \
    gld16(g_ + 1024, &stg[wave][slot][512]);                                   \
    gld16(g_ + 2048, &stg[wave][slot][1024]);                                  \
    gld16(g_ + 3072, &stg[wave][slot][1536]);                                  \
    SBAR();                                                                    \
  } while (0)
// Gate chunk: 8 frags (8KB), 8 ops, exact pointers, offset=0.
#define DMA8G(cbyte, slot)                                                     \
  do {                                                                         \
    SBAR();                                                                    \
    const char* g_ = wbase8 + (cbyte);                                         \
    gld16(g_,        &stg[wave][slot][0]);                                     \
    gld16(g_ + 1024, &stg[wave][slot][512]);                                   \
    gld16(g_ + 2048, &stg[wave][slot][1024]);                                  \
    gld16(g_ + 3072, &stg[wave][slot][1536]);                                  \
    gld16(g_ + 4096, &stg[wave][slot][2048]);                                  \
    gld16(g_ + 5120, &stg[wave][slot][2560]);                                  \
    gld16(g_ + 6144, &stg[wave][slot][3072]);                                  \
    gld16(g_ + 7168, &stg[wave][slot][3584]);                                  \
    SBAR();                                                                    \
  } while (0)

// Consume head half-chunk (frags -> hfr[h4..h4+3]) into hacc.
#define CHEAD(h4, slot, N)                                                     \
  do {                                                                         \
    asm volatile("s_waitcnt vmcnt(" #N ")" ::: "memory");                      \
    SBAR();                                                                    \
    _Pragma("unroll")                                                          \
    for (int j_ = 0; j_ < 4; ++j_) {                                           \
      s16x8 b_ = *(const s16x8*)&stg[wave][slot][j_ * 512 + lane * 8];         \
      hacc = __builtin_amdgcn_mfma_f32_16x16x32_bf16(hfr[(h4) + j_], b_,       \
                                                     hacc, 0, 0, 0);           \
    }                                                                          \
    asm volatile("s_waitcnt lgkmcnt(0)" ::: "memory");                         \
    SBAR();                                                                    \
  } while (0)
// Consume gate chunk (8 frags, qm=0..7) with A-frag af into acc2[qm].
#define CGATE(af, slot, N)                                                     \
  do {                                                                         \
    asm volatile("s_waitcnt vmcnt(" #N ")" ::: "memory");                      \
    SBAR();                                                                    \
    _Pragma("unroll")                                                          \
    for (int s_ = 0; s_ < 8; ++s_) {                                           \
      s16x8 b_ = *(const s16x8*)&stg[wave][slot][s_ * 512 + lane * 8];         \
      acc2[s_] = __builtin_amdgcn_mfma_f32_16x16x32_bf16((af), b_,             \
                                                         acc2[s_], 0, 0, 0);   \
    }                                                                          \
    asm volatile("s_waitcnt lgkmcnt(0)" ::: "memory");                         \
    SBAR();                                                                    \
  } while (0)

__global__ __launch_bounds__(NT, 2) void rnn_kernel(
    const float* __restrict__ x,
    const float* __restrict__ b_ih, const float* __restrict__ b_hh,
    const float* __restrict__ pit_b1, const float* __restrict__ pit_w2,
    const float* __restrict__ pit_b2,
    const float* __restrict__ time_w1, const float* __restrict__ time_b1,
    const float* __restrict__ time_w2, const float* __restrict__ time_b2,
    const float* __restrict__ ar_w1, const float* __restrict__ ar_b1,
    const float* __restrict__ ar_b2,
    const unsigned short* __restrict__ ws,
    float* __restrict__ out)
{
  __shared__ __align__(16) unsigned short A_lds[16][ALD];    // [x(64) | h(256)]
  __shared__ __align__(16) unsigned short xo_lds[16][XLD];   // x_orig[t]
  __shared__ __align__(16) unsigned short ar1_lds[16][XLD];  // relu(ar1)
  __shared__ __align__(16) unsigned short stg[8][2][4096];   // DMA ring (128 KB)
  __shared__ float pitp[4][16];
  __shared__ float timep[4][16];

  const int tid  = threadIdx.x;
  const int wave = tid >> 6;
  const int lane = tid & 63;
  const int lrow = lane & 15;
  const int lgrp = lane >> 4;
  const int b0   = blockIdx.x * 16;
  const int hcol = (wave & 3) * 16 + lrow;
  const char* wbase8 = (const char*)ws + wave * WSTRIDE + lane * 16;

  for (int i = tid; i < 16 * ALD; i += NT) (&A_lds[0][0])[i] = 0;

  // ---- role constants ----
  float gbias[8];
#pragma unroll
  for (int qm = 0; qm < 8; ++qm) {
    int g = (qm >> 1) * 256 + wave * 32 + (qm & 1) * 16 + lrow;
    gbias[qm] = b_ih[g] + b_hh[g];
  }
  s16x8 arw[2];
  float pb1v = 0, pw2v = 0, tb1v = 0, tw2v = 0, twlv = 0;
  float ab1v = 0, arpv = 0, artv = 0, ab2v = 0;
  if (wave < 4) {
    arw[0] = *(const s16x8*)&ws[WS_AXF + ((wave & 3) * 2 + 0) * 512 + lane * 8];
    arw[1] = *(const s16x8*)&ws[WS_AXF + ((wave & 3) * 2 + 1) * 512 + lane * 8];
    pb1v = pit_b1[hcol]; pw2v = pit_w2[hcol];
    ab1v = ar_b1[hcol];  arpv = ar_w1[hcol * 66]; artv = ar_w1[hcol * 66 + 1];
  } else {
    arw[0] = *(const s16x8*)&ws[WS_A2F + ((wave & 3) * 2 + 0) * 512 + lane * 8];
    arw[1] = *(const s16x8*)&ws[WS_A2F + ((wave & 3) * 2 + 1) * 512 + lane * 8];
    tb1v = time_b1[hcol]; tw2v = time_w2[hcol];
    twlv = time_w1[hcol * 257 + 256]; ab2v = ar_b2[hcol];
  }
  const float pb2 = pit_b2[0], tb2 = time_b2[0];

  // ---- stage x[:,0,:], write ar_out[:,0,:] ----
  const int srow = tid >> 5;
  const int sc2  = (tid & 31) * 2;
  const size_t xbase = (size_t)(b0 + srow) * S_LEN * I_DIM + sc2;
  float2 xpre = *reinterpret_cast<const float2*>(&x[xbase]);
  __syncthreads();
  A_lds[srow][sc2]     = f2bf(xpre.x);
  A_lds[srow][sc2 + 1] = f2bf(xpre.y);
  *reinterpret_cast<float2*>(&out[OUT_AR + xbase]) = xpre;

  float cst[2][4];
#pragma unroll
  for (int m = 0; m < 2; ++m)
#pragma unroll
    for (int r = 0; r < 4; ++r) cst[m][r] = 0.0f;
  __syncthreads();

  // ---- prologue: gates(0) = bias + x0-part (h=0); kt0 @73728, kt1 @81920 ----
  f32x4 acc2[8];
#pragma unroll
  for (int qm = 0; qm < 8; ++qm) {
    f32x4 tv; tv[0] = tv[1] = tv[2] = tv[3] = gbias[qm];
    acc2[qm] = tv;
  }
  {
    s16x8 a0 = AFRAG(0);
#pragma unroll
    for (int qm = 0; qm < 8; ++qm) {
      s16x8 b = *(const s16x8*)(wbase8 + 73728 + qm * 1024);
      acc2[qm] = __builtin_amdgcn_mfma_f32_16x16x32_bf16(a0, b, acc2[qm], 0, 0, 0);
    }
    s16x8 a1 = AFRAG(1);
#pragma unroll
    for (int qm = 0; qm < 8; ++qm) {
      s16x8 b = *(const s16x8*)(wbase8 + 81920 + qm * 1024);
      acc2[qm] = __builtin_amdgcn_mfma_f32_16x16x32_bf16(a1, b, acc2[qm], 0, 0, 0);
    }
  }
  // drain prologue's plain loads so ring counts start clean, then prime ring
  asm volatile("s_waitcnt vmcnt(0)" ::: "memory");
  SBAR();
  DMA4H(0, 0);      // c0 = h0 (slot0)
  DMA4H(4096, 1);   // c1 = h1 (slot1)

  // =========================== time loop ===========================
  for (int t = 0; t < S_LEN; ++t) {
    // ---- P0: xo stage, x prefetch, LSTM -> h ----
    xo_lds[srow][sc2]     = f2bf(xpre.x);
    xo_lds[srow][sc2 + 1] = f2bf(xpre.y);
    if (t + 1 < S_LEN)
      xpre = *reinterpret_cast<const float2*>(&x[xbase + (size_t)(t + 1) * I_DIM]);

#pragma unroll
    for (int m = 0; m < 2; ++m)
#pragma unroll
      for (int r = 0; r < 4; ++r) {
        float ig = sigf(acc2[0 + m][r]);
        float fg = sigf(acc2[2 + m][r]);
        float gg = tanh_fast(acc2[4 + m][r]);
        float og = sigf(acc2[6 + m][r]);
        float c  = fg * cst[m][r] + ig * gg;
        cst[m][r] = c;
        A_lds[lgrp * 4 + r][64 + wave * 32 + m * 16 + lrow] = f2bf(og * tanh_fast(c));
      }
#pragma unroll
    for (int qm = 0; qm < 8; ++qm) {
      f32x4 tv; tv[0] = tv[1] = tv[2] = tv[3] = gbias[qm];
      acc2[qm] = tv;
    }
    sync_lds();  // barrier A: h + xo ready

    // ---- P1: heads (c0,c1); pit reduce; gate chunks c2..c5 (kt2-5) ----
    s16x8 hfr[8];
#pragma unroll
    for (int k = 0; k < 8; ++k)
      hfr[k] = *(const s16x8*)&A_lds[lrow][64 + k * 32 + 8 * lgrp];

    f32x4 hacc;
    {
      float hb = (wave < 4) ? pb1v : tb1v;
      hacc[0] = hacc[1] = hacc[2] = hacc[3] = hb;
    }
    CHEAD(0, 0, 4); DMA8G(8192, 0);    // c0 (h frags 0-3) -> issue c2 (kt2)
    CHEAD(4, 1, 8); DMA8G(16384, 1);   // c1 (h frags 4-7) -> c3 (kt3)

    if (wave < 4) {  // pit partial reduce
      float v[4];
#pragma unroll
      for (int r = 0; r < 4; ++r) v[r] = fmaxf(hacc[r], 0.0f) * pw2v;
#pragma unroll
      for (int off = 1; off < 16; off <<= 1)
#pragma unroll
        for (int r = 0; r < 4; ++r) v[r] += __shfl_xor(v[r], off);
      if (lrow == 0) {
#pragma unroll
        for (int r = 0; r < 4; ++r) pitp[wave][lgrp * 4 + r] = v[r];
      }
    }
    CGATE(hfr[0], 0, 8); DMA8G(24576, 0);  // c2 (kt2) -> c4 (kt4)
    CGATE(hfr[1], 1, 8); DMA8G(32768, 1);  // c3 (kt3) -> c5 (kt5)
    CGATE(hfr[2], 0, 8); DMA8G(40960, 0);  // c4 (kt4) -> c6 (kt6)
    CGATE(hfr[3], 1, 8); DMA8G(49152, 1);  // c5 (kt5) -> c7 (kt7)
    sync_lds();  // barrier 1: pit partials ready

    // ---- P2: pv; time finish / ar1-x; pit out; chunks c6,c7 (kt6,7) ----
    float pv[4];
#pragma unroll
    for (int r = 0; r < 4; ++r) {
      int row = lgrp * 4 + r;
      pv[r] = pitp[0][row] + pitp[1][row] + pitp[2][row] + pitp[3][row] + pb2;
    }
    f32x4 aracc;
    if (wave < 4) {
      aracc[0] = aracc[1] = aracc[2] = aracc[3] = ab1v;
#pragma unroll
      for (int kt = 0; kt < 2; ++kt) {
        s16x8 aX = *(const s16x8*)&xo_lds[lrow][kt * 32 + 8 * lgrp];
        aracc = __builtin_amdgcn_mfma_f32_16x16x32_bf16(aX, arw[kt], aracc, 0, 0, 0);
      }
      if (wave == 0 && lane < 16) {
        float pvs = pitp[0][lane] + pitp[1][lane] + pitp[2][lane] + pitp[3][lane] + pb2;
        out[OUT_PIT + (size_t)(b0 + lane) * S_LEN + t] = pvs;
      }
    } else {
      float v[4];
#pragma unroll
      for (int r = 0; r < 4; ++r)
        v[r] = fmaxf(hacc[r] + pv[r] * twlv, 0.0f) * tw2v;
#pragma unroll
      for (int off = 1; off < 16; off <<= 1)
#pragma unroll
        for (int r = 0; r < 4; ++r) v[r] += __shfl_xor(v[r], off);
      if (lrow == 0) {
#pragma unroll
        for (int r = 0; r < 4; ++r) timep[wave & 3][lgrp * 4 + r] = v[r];
      }
    }
    CGATE(hfr[4], 0, 8); DMA8G(57344, 0);  // c6 (kt6) -> c8 (kt8)
    CGATE(hfr[5], 1, 8); DMA8G(65536, 1);  // c7 (kt7) -> c9 (kt9)
    sync_lds();  // barrier 2: time partials ready

    // ---- P3: tv; ar1 finish; time out; chunks c8,c9 (kt8,9) ----
    float tvv[4];
#pragma unroll
    for (int r = 0; r < 4; ++r) {
      int row = lgrp * 4 + r;
      tvv[r] = timep[0][row] + timep[1][row] + timep[2][row] + timep[3][row] + tb2;
    }
    if (wave < 4) {
#pragma unroll
      for (int r = 0; r < 4; ++r) {
        float a1 = aracc[r] + pv[r] * arpv + tvv[r] * artv;
        ar1_lds[lgrp * 4 + r][hcol] = f2bf(fmaxf(a1, 0.0f));
      }
    } else if (wave == 4 && lane < 16) {
      float tvs = timep[0][lane] + timep[1][lane] + timep[2][lane] + timep[3][lane] + tb2;
      out[OUT_TIME + (size_t)(b0 + lane) * S_LEN + t] = tvs;
    }
    CGATE(hfr[6], 0, 8); DMA8G(73728, 0);  // c8 (kt8) -> c10 (kt0)
    CGATE(hfr[7], 1, 8); DMA8G(81920, 1);  // c9 (kt9) -> c11 (kt1)
    sync_lds();  // barrier 3: ar1 ready

    // ---- P4: ar2 -> x_{t+1} (waves 4-7) ----
    if (wave >= 4) {
      f32x4 nacc;
      nacc[0] = nacc[1] = nacc[2] = nacc[3] = ab2v;
#pragma unroll
      for (int kt = 0; kt < 2; ++kt) {
        s16x8 aR = *(const s16x8*)&ar1_lds[lrow][kt * 32 + 8 * lgrp];
        nacc = __builtin_amdgcn_mfma_f32_16x16x32_bf16(aR, arw[kt], nacc, 0, 0, 0);
      }
#pragma unroll
      for (int r = 0; r < 4; ++r) {
        int row = lgrp * 4 + r;
        A_lds[row][hcol] = f2bf(nacc[r]);
        if (t < S_LEN - 1)
          out[OUT_AR + (size_t)(b0 + row) * S_LEN * I_DIM + (size_t)(t + 1) * I_DIM + hcol] = nacc[r];
      }
    }
    sync_lds();  // barrier B: x_{t+1} staged

    // ---- P5: gates-x chunks c10,c11 (kt0,1); prime next step's heads ----
    {
      s16x8 a0 = AFRAG(0);
      CGATE(a0, 0, 8); DMA4H(0, 0);      // c10 (kt0) -> c0' (h0')
      s16x8 a1 = AFRAG(1);
      CGATE(a1, 1, 4); DMA4H(4096, 1);   // c11 (kt1) -> c1' (h1')
    }
  }
}

extern "C" void kernel_launch(void* const* d_in, const int* in_sizes, int n_in,
                              void* d_out, int out_size, void* d_ws, size_t ws_size,
                              hipStream_t stream) {
  const float* x       = (const float*)d_in[0];
  const float* w_ih    = (const float*)d_in[1];
  const float* w_hh    = (const float*)d_in[2];
  const float* b_ih    = (const float*)d_in[3];
  const float* b_hh    = (const float*)d_in[4];
  const float* pit_w1  = (const float*)d_in[5];
  const float* pit_b1  = (const float*)d_in[6];
  const float* pit_w2  = (const float*)d_in[7];
  const float* pit_b2  = (const float*)d_in[8];
  const float* time_w1 = (const float*)d_in[9];
  const float* time_b1 = (const float*)d_in[10];
  const float* time_w2 = (const float*)d_in[11];
  const float* time_b2 = (const float*)d_in[12];
  const float* ar_w1   = (const float*)d_in[13];
  const float* ar_b1   = (const float*)d_in[14];
  const float* ar_w2   = (const float*)d_in[15];
  const float* ar_b2   = (const float*)d_in[16];
  unsigned short* ws   = (unsigned short*)d_ws;
  float* out           = (float*)d_out;

  prep_kernel<<<dim3((WS_TOTAL + 255) / 256), dim3(256), 0, stream>>>(
      w_ih, w_hh, pit_w1, time_w1, ar_w1, ar_w2, ws);
  rnn_kernel<<<dim3(16), dim3(NT), 0, stream>>>(
      x, b_ih, b_hh, pit_b1, pit_w2, pit_b2,
      time_w1, time_b1, time_w2, time_b2,
      ar_w1, ar_b1, ar_b2, ws, out);
}

// Round 14
// 3490.121 us; speedup vs baseline: 2.1794x; 2.1794x over previous
//
#include <hip/hip_runtime.h>
#include <hip/hip_bf16.h>
#include <hip/hip_fp8.h>

// ---------------------------------------------------------------------------
// UnifiedModelRNN: B=256,S=512,I=64,H=256. 16 blocks x 512 threads (8 waves,
// 2/SIMD); block g owns batch rows [16g,16g+16). No grid sync.
// R14 = R8 structure with fp8-e4m3 GATE path (weights + gate A-operands):
//  * Gate weights quantized to fp8 in prep (consume-order stream, 40KB/wave):
//    frags 512B; kt order kt2..kt9,kt0,kt1 (ktidx 0..9). L2 stream halves
//    (640->320 KB/step) and LDS ring traffic halves.
//  * Gates GEMM via mfma_f32_16x16x32_fp8_fp8 (same shape/fragment geometry,
//    B-frag = ds_read_b64). A-operand: fp8 copy of [x|h] in A_f8 (c-state
//    stays f32 in regs; heads/pit/time/ar stay bf16 -> error stays small).
//  * DMA ring: R8-proven protocol — 2 slots/wave (8x2x4KB=64KB), chunk =
//    full kt (4 ops), consume c {vmcnt(4); 8 ds_read_b64+MFMA; lgkmcnt(0)}
//    -> issue c+2. offset=0 exact-pointer DMAs (imm-offset arg is broken).
//  * pit/time head weights LDS-resident (bf16); ar weights in registers.
//  * lgkm-only barriers (DMA rides across phases).
// ---------------------------------------------------------------------------

typedef float f32x4 __attribute__((ext_vector_type(4)));
typedef short s16x8 __attribute__((ext_vector_type(8)));

#define S_LEN 512
#define I_DIM 64
#define NT    512

// ws byte offsets
#define WSB_G8   0        // fp8 gate stream: 8 waves x 80 frags x 512B = 320KB
#define WSTRIDE8 40960    // bytes per wave gate stream
#define WSB_BF   327680   // bf16 region (u16 elems): pit 16384, tim 16384,
                          //   arx 4096, ar2 4096  (total 40960 elems)
#define PREP_N   368640   // 327680 fp8 bytes + 40960 bf16 elems

#define OUT_PIT  0
#define OUT_TIME 131072
#define OUT_AR   262144

#define ALD 328   // bf16 [x|h] row stride (elems)
#define AF8 336   // fp8  [x|h] row stride (bytes)
#define XLD 72

__device__ __forceinline__ float sigf(float x) {
  return 1.0f / (1.0f + __expf(-x));
}
__device__ __forceinline__ float tanh_fast(float x) {
  float c = fminf(fmaxf(x, -15.0f), 15.0f);
  float e = __expf(2.0f * c);
  return (e - 1.0f) / (e + 1.0f);
}
__device__ __forceinline__ unsigned short f2bf(float f) {
  __hip_bfloat16 h = __float2bfloat16(f);
  return *reinterpret_cast<unsigned short*>(&h);
}
__device__ __forceinline__ unsigned char f2f8(float v) {
  __hip_fp8_e4m3 q(v);
  return *reinterpret_cast<unsigned char*>(&q);
}
// LDS-only barrier: does NOT drain vmcnt -> DMA stays in flight.
__device__ __forceinline__ void sync_lds() {
  asm volatile("s_waitcnt lgkmcnt(0)" ::: "memory");
  __builtin_amdgcn_s_barrier();
  asm volatile("" ::: "memory");
}
// 16B/lane global->LDS DMA, offset=0, exact pointers (proven form).
__device__ __forceinline__ void gld16(const void* g, void* l) {
  __builtin_amdgcn_global_load_lds(
      (const __attribute__((address_space(1))) unsigned int*)g,
      (__attribute__((address_space(3))) unsigned int*)l, 16, 0, 0);
}

__global__ void prep_kernel(const float* __restrict__ w_ih,
                            const float* __restrict__ w_hh,
                            const float* __restrict__ pit_w1,
                            const float* __restrict__ time_w1,
                            const float* __restrict__ ar_w1,
                            const float* __restrict__ ar_w2,
                            unsigned char* __restrict__ ws8) {
  int idx = blockIdx.x * 256 + threadIdx.x;
  if (idx >= PREP_N) return;
  if (idx < WSB_G8 + 327680) {
    // fp8 gate byte
    int w  = idx / WSTRIDE8;
    int p8 = idx - w * WSTRIDE8;     // 0..40959
    int f  = p8 >> 9;                // frag 0..79
    int b  = p8 & 511;
    int lane = b >> 3, e = b & 7;
    int lrow = lane & 15, lgrp = lane >> 4;
    int ktidx = f >> 3, qm = f & 7;
    int kt = (ktidx < 8) ? ktidx + 2 : ktidx - 8;   // kt2..kt9,kt0,kt1
    int row = (qm >> 1) * 256 + w * 32 + (qm & 1) * 16 + lrow;
    int col = kt * 32 + lgrp * 8 + e;
    float v = (col < I_DIM) ? w_ih[row * I_DIM + col]
                            : w_hh[row * 256 + col - I_DIM];
    ws8[idx] = f2f8(v);
  } else {
    // bf16 element
    int e2 = idx - 327680;           // 0..40959
    int lane = (e2 >> 3) & 63;
    int e    = e2 & 7;
    int lrow = lane & 15, lgrp = lane >> 4;
    float v;
    if (e2 < 16384) {                // pit_w1: frag f = wv*8+kt
      int f = e2 >> 9, wv = f >> 3, kt = f & 7;
      v = pit_w1[(wv * 16 + lrow) * 256 + kt * 32 + lgrp * 8 + e];
    } else if (e2 < 32768) {         // time_w1[:, :256]
      int f = (e2 - 16384) >> 9, wv = f >> 3, kt = f & 7;
      v = time_w1[(wv * 16 + lrow) * 257 + kt * 32 + lgrp * 8 + e];
    } else if (e2 < 36864) {         // ar_w1[:, 2:66]: frag f = wv*2+kt
      int f = (e2 - 32768) >> 9, wv = f >> 1, kt = f & 1;
      v = ar_w1[(wv * 16 + lrow) * 66 + 2 + kt * 32 + lgrp * 8 + e];
    } else {                         // ar_w2
      int f = (e2 - 36864) >> 9, wv = f >> 1, kt = f & 1;
      v = ar_w2[(wv * 16 + lrow) * 64 + kt * 32 + lgrp * 8 + e];
    }
    ((unsigned short*)(ws8 + WSB_BF))[e2] = f2bf(v);
  }
}

// fp8 A-frag from A_f8 (byte cols): 8 bytes/lane.
#define A8FRAG(kt) (*(const long*)&A_f8[lrow][(kt) * 32 + 8 * lgrp])

// DMA one full fp8 kt chunk (4KB = 4 ops) into stg8[wave][slot].
#define DMA4F(ktidx, slot)                                                     \
  do {                                                                         \
    const unsigned char* g_ = wg8l + (ktidx) * 4096;                           \
    gld16(g_,        &stg8[wave][slot][0]);                                    \
    gld16(g_ + 1024, &stg8[wave][slot][1024]);                                 \
    gld16(g_ + 2048, &stg8[wave][slot][2048]);                                 \
    gld16(g_ + 3072, &stg8[wave][slot][3072]);                                 \
  } while (0)

// Consume fp8 gate chunk (8 frags qm=0..7) with fp8 A-frag af into acc2[qm].
// vmcnt(4): this chunk landed, next chunk's 4 ops still in flight.
#define GCHUNK8(af, slot)                                                      \
  do {                                                                         \
    asm volatile("s_waitcnt vmcnt(4)" ::: "memory");                           \
    _Pragma("unroll")                                                          \
    for (int s_ = 0; s_ < 8; ++s_) {                                           \
      long b_ = *(const long*)&stg8[wave][slot][s_ * 512 + lane * 8];          \
      acc2[s_] = __builtin_amdgcn_mfma_f32_16x16x32_fp8_fp8(                   \
          (af), b_, acc2[s_], 0, 0, 0);                                        \
    }                                                                          \
    asm volatile("s_waitcnt lgkmcnt(0)" ::: "memory");                         \
  } while (0)

__global__ __launch_bounds__(NT, 2) void rnn_kernel(
    const float* __restrict__ x,
    const float* __restrict__ b_ih, const float* __restrict__ b_hh,
    const float* __restrict__ pit_b1, const float* __restrict__ pit_w2,
    const float* __restrict__ pit_b2,
    const float* __restrict__ time_w1, const float* __restrict__ time_b1,
    const float* __restrict__ time_w2, const float* __restrict__ time_b2,
    const float* __restrict__ ar_w1, const float* __restrict__ ar_b1,
    const float* __restrict__ ar_b2,
    const unsigned char* __restrict__ ws8,
    float* __restrict__ out)
{
  __shared__ __align__(16) unsigned short A_lds[16][ALD];    // bf16 [x|h] (heads)
  __shared__ __align__(16) unsigned char  A_f8[16][AF8];     // fp8  [x|h] (gates)
  __shared__ __align__(16) unsigned short xo_lds[16][XLD];   // x_orig[t] bf16
  __shared__ __align__(16) unsigned short ar1_lds[16][XLD];  // relu(ar1) bf16
  __shared__ __align__(16) unsigned short pit_lds[32 * 512]; // pit_w1 (32 KB)
  __shared__ __align__(16) unsigned short tim_lds[32 * 512]; // time_w1 (32 KB)
  __shared__ __align__(16) unsigned char  stg8[8][2][4096];  // fp8 DMA ring (64 KB)
  __shared__ float pitp[4][16];
  __shared__ float timep[4][16];

  const int tid  = threadIdx.x;
  const int wave = tid >> 6;
  const int lane = tid & 63;
  const int lrow = lane & 15;
  const int lgrp = lane >> 4;
  const int b0   = blockIdx.x * 16;
  const int hcol = (wave & 3) * 16 + lrow;
  const unsigned char* wg8l = ws8 + wave * WSTRIDE8 + lane * 16;  // DMA base
  const unsigned char* wg8  = ws8 + wave * WSTRIDE8;              // frag reads
  const unsigned short* wsb = (const unsigned short*)(ws8 + WSB_BF);

  // ---- one-time LDS staging: pit/tim bf16 weights ----
  for (int c = tid; c < 2048; c += NT) {
    *(s16x8*)&pit_lds[c * 8] = *(const s16x8*)&wsb[c * 8];
    *(s16x8*)&tim_lds[c * 8] = *(const s16x8*)&wsb[16384 + c * 8];
  }
  for (int i = tid; i < 16 * ALD; i += NT) (&A_lds[0][0])[i] = 0;

  // ---- role constants ----
  float gbias[8];
#pragma unroll
  for (int qm = 0; qm < 8; ++qm) {
    int g = (qm >> 1) * 256 + wave * 32 + (qm & 1) * 16 + lrow;
    gbias[qm] = b_ih[g] + b_hh[g];
  }
  s16x8 arw[2];
  float pb1v = 0, pw2v = 0, tb1v = 0, tw2v = 0, twlv = 0;
  float ab1v = 0, arpv = 0, artv = 0, ab2v = 0;
  if (wave < 4) {
    arw[0] = *(const s16x8*)&wsb[32768 + ((wave & 3) * 2 + 0) * 512 + lane * 8];
    arw[1] = *(const s16x8*)&wsb[32768 + ((wave & 3) * 2 + 1) * 512 + lane * 8];
    pb1v = pit_b1[hcol]; pw2v = pit_w2[hcol];
    ab1v = ar_b1[hcol];  arpv = ar_w1[hcol * 66]; artv = ar_w1[hcol * 66 + 1];
  } else {
    arw[0] = *(const s16x8*)&wsb[36864 + ((wave & 3) * 2 + 0) * 512 + lane * 8];
    arw[1] = *(const s16x8*)&wsb[36864 + ((wave & 3) * 2 + 1) * 512 + lane * 8];
    tb1v = time_b1[hcol]; tw2v = time_w2[hcol];
    twlv = time_w1[hcol * 257 + 256]; ab2v = ar_b2[hcol];
  }
  const float pb2 = pit_b2[0], tb2 = time_b2[0];

  // ---- stage x[:,0,:] (bf16 + fp8), write ar_out[:,0,:] ----
  const int srow = tid >> 5;
  const int sc2  = (tid & 31) * 2;
  const size_t xbase = (size_t)(b0 + srow) * S_LEN * I_DIM + sc2;
  float2 xpre = *reinterpret_cast<const float2*>(&x[xbase]);
  __syncthreads();
  A_lds[srow][sc2]     = f2bf(xpre.x);
  A_lds[srow][sc2 + 1] = f2bf(xpre.y);
  A_f8[srow][sc2]      = f2f8(xpre.x);
  A_f8[srow][sc2 + 1]  = f2f8(xpre.y);
  *reinterpret_cast<float2*>(&out[OUT_AR + xbase]) = xpre;

  float cst[2][4];
#pragma unroll
  for (int m = 0; m < 2; ++m)
#pragma unroll
    for (int r = 0; r < 4; ++r) cst[m][r] = 0.0f;
  __syncthreads();

  // ---- prologue: gates(0) = bias + x0-part (h=0); kt0=frags 64+, kt1=72+ ----
  f32x4 acc2[8];
#pragma unroll
  for (int qm = 0; qm < 8; ++qm) {
    f32x4 tv; tv[0] = tv[1] = tv[2] = tv[3] = gbias[qm];
    acc2[qm] = tv;
  }
  {
    long a0 = A8FRAG(0);
#pragma unroll
    for (int qm = 0; qm < 8; ++qm) {
      long b = *(const long*)(wg8 + (64 + qm) * 512 + lane * 8);
      acc2[qm] = __builtin_amdgcn_mfma_f32_16x16x32_fp8_fp8(a0, b, acc2[qm], 0, 0, 0);
    }
    long a1 = A8FRAG(1);
#pragma unroll
    for (int qm = 0; qm < 8; ++qm) {
      long b = *(const long*)(wg8 + (72 + qm) * 512 + lane * 8);
      acc2[qm] = __builtin_amdgcn_mfma_f32_16x16x32_fp8_fp8(a1, b, acc2[qm], 0, 0, 0);
    }
  }
  // drain prologue plain loads, then prime the ring: kt2 -> slot0, kt3 -> slot1
  asm volatile("s_waitcnt vmcnt(0)" ::: "memory");
  DMA4F(0, 0);
  DMA4F(1, 1);

  // =========================== time loop ===========================
  for (int t = 0; t < S_LEN; ++t) {
    // ---- P0: xo stage, x prefetch, LSTM -> h (bf16 + fp8) ----
    xo_lds[srow][sc2]     = f2bf(xpre.x);
    xo_lds[srow][sc2 + 1] = f2bf(xpre.y);
    if (t + 1 < S_LEN)
      xpre = *reinterpret_cast<const float2*>(&x[xbase + (size_t)(t + 1) * I_DIM]);

#pragma unroll
    for (int m = 0; m < 2; ++m)
#pragma unroll
      for (int r = 0; r < 4; ++r) {
        float ig = sigf(acc2[0 + m][r]);
        float fg = sigf(acc2[2 + m][r]);
        float gg = tanh_fast(acc2[4 + m][r]);
        float og = sigf(acc2[6 + m][r]);
        float c  = fg * cst[m][r] + ig * gg;
        cst[m][r] = c;
        float hv = og * tanh_fast(c);
        int row = lgrp * 4 + r, col = 64 + wave * 32 + m * 16 + lrow;
        A_lds[row][col] = f2bf(hv);
        A_f8[row][col]  = f2f8(hv);
      }
#pragma unroll
    for (int qm = 0; qm < 8; ++qm) {
      f32x4 tv; tv[0] = tv[1] = tv[2] = tv[3] = gbias[qm];
      acc2[qm] = tv;
    }
    sync_lds();  // barrier A: h + xo ready

    // ---- P1: heads (bf16, LDS-resident W); pit reduce; gates kt2-5 ----
    s16x8 hfr[8];
    long  hfr8[8];
#pragma unroll
    for (int k = 0; k < 8; ++k) {
      hfr[k]  = *(const s16x8*)&A_lds[lrow][64 + k * 32 + 8 * lgrp];
      hfr8[k] = *(const long*)&A_f8[lrow][64 + k * 32 + 8 * lgrp];
    }
    f32x4 hacc;
    {
      float hb = (wave < 4) ? pb1v : tb1v;
      hacc[0] = hacc[1] = hacc[2] = hacc[3] = hb;
      const unsigned short* hbp = (wave < 4) ? pit_lds : tim_lds;
#pragma unroll
      for (int kt = 0; kt < 8; ++kt) {
        s16x8 bH = *(const s16x8*)&hbp[(((wave & 3) * 8 + kt) * 64 + lane) * 8];
        hacc = __builtin_amdgcn_mfma_f32_16x16x32_bf16(hfr[kt], bH, hacc, 0, 0, 0);
      }
    }
    if (wave < 4) {  // pit partial reduce
      float v[4];
#pragma unroll
      for (int r = 0; r < 4; ++r) v[r] = fmaxf(hacc[r], 0.0f) * pw2v;
#pragma unroll
      for (int off = 1; off < 16; off <<= 1)
#pragma unroll
        for (int r = 0; r < 4; ++r) v[r] += __shfl_xor(v[r], off);
      if (lrow == 0) {
#pragma unroll
        for (int r = 0; r < 4; ++r) pitp[wave][lgrp * 4 + r] = v[r];
      }
    }
    GCHUNK8(hfr8[0], 0); DMA4F(2, 0);   // kt2 -> issue kt4
    GCHUNK8(hfr8[1], 1); DMA4F(3, 1);   // kt3 -> kt5
    GCHUNK8(hfr8[2], 0); DMA4F(4, 0);   // kt4 -> kt6
    GCHUNK8(hfr8[3], 1); DMA4F(5, 1);   // kt5 -> kt7
    sync_lds();  // barrier 1: pit partials ready

    // ---- P2: pv; time finish / ar1-x; pit out; gates kt6,kt7 ----
    float pv[4];
#pragma unroll
    for (int r = 0; r < 4; ++r) {
      int row = lgrp * 4 + r;
      pv[r] = pitp[0][row] + pitp[1][row] + pitp[2][row] + pitp[3][row] + pb2;
    }
    f32x4 aracc;
    if (wave < 4) {
      aracc[0] = aracc[1] = aracc[2] = aracc[3] = ab1v;
#pragma unroll
      for (int kt = 0; kt < 2; ++kt) {
        s16x8 aX = *(const s16x8*)&xo_lds[lrow][kt * 32 + 8 * lgrp];
        aracc = __builtin_amdgcn_mfma_f32_16x16x32_bf16(aX, arw[kt], aracc, 0, 0, 0);
      }
      if (wave == 0 && lane < 16) {
        float pvs = pitp[0][lane] + pitp[1][lane] + pitp[2][lane] + pitp[3][lane] + pb2;
        out[OUT_PIT + (size_t)(b0 + lane) * S_LEN + t] = pvs;
      }
    } else {
      float v[4];
#pragma unroll
      for (int r = 0; r < 4; ++r)
        v[r] = fmaxf(hacc[r] + pv[r] * twlv, 0.0f) * tw2v;
#pragma unroll
      for (int off = 1; off < 16; off <<= 1)
#pragma unroll
        for (int r = 0; r < 4; ++r) v[r] += __shfl_xor(v[r], off);
      if (lrow == 0) {
#pragma unroll
        for (int r = 0; r < 4; ++r) timep[wave & 3][lgrp * 4 + r] = v[r];
      }
    }
    GCHUNK8(hfr8[4], 0); DMA4F(6, 0);   // kt6 -> kt8
    GCHUNK8(hfr8[5], 1); DMA4F(7, 1);   // kt7 -> kt9
    sync_lds();  // barrier 2: time partials ready

    // ---- P3: tv; ar1 finish; time out; gates kt8,kt9 ----
    float tvv[4];
#pragma unroll
    for (int r = 0; r < 4; ++r) {
      int row = lgrp * 4 + r;
      tvv[r] = timep[0][row] + timep[1][row] + timep[2][row] + timep[3][row] + tb2;
    }
    if (wave < 4) {
#pragma unroll
      for (int r = 0; r < 4; ++r) {
        float a1 = aracc[r] + pv[r] * arpv + tvv[r] * artv;
        ar1_lds[lgrp * 4 + r][hcol] = f2bf(fmaxf(a1, 0.0f));
      }
    } else if (wave == 4 && lane < 16) {
      float tvs = timep[0][lane] + timep[1][lane] + timep[2][lane] + timep[3][lane] + tb2;
      out[OUT_TIME + (size_t)(b0 + lane) * S_LEN + t] = tvs;
    }
    GCHUNK8(hfr8[6], 0); DMA4F(8, 0);   // kt8 -> kt0
    GCHUNK8(hfr8[7], 1); DMA4F(9, 1);   // kt9 -> kt1
    sync_lds();  // barrier 3: ar1 ready

    // ---- P4: ar2 -> x_{t+1} (waves 4-7), bf16 + fp8 ----
    if (wave >= 4) {
      f32x4 nacc;
      nacc[0] = nacc[1] = nacc[2] = nacc[3] = ab2v;
#pragma unroll
      for (int kt = 0; kt < 2; ++kt) {
        s16x8 aR = *(const s16x8*)&ar1_lds[lrow][kt * 32 + 8 * lgrp];
        nacc = __builtin_amdgcn_mfma_f32_16x16x32_bf16(aR, arw[kt], nacc, 0, 0, 0);
      }
#pragma unroll
      for (int r = 0; r < 4; ++r) {
        int row = lgrp * 4 + r;
        float nv = nacc[r];
        A_lds[row][hcol] = f2bf(nv);
        A_f8[row][hcol]  = f2f8(nv);
        if (t < S_LEN - 1)
          out[OUT_AR + (size_t)(b0 + row) * S_LEN * I_DIM + (size_t)(t + 1) * I_DIM + hcol] = nv;
      }
    }
    sync_lds();  // barrier B: x_{t+1} staged

    // ---- P5: gates-x kt0,kt1; prime next step's kt2,kt3 ----
    {
      long a0 = A8FRAG(0);
      GCHUNK8(a0, 0); DMA4F(0, 0);      // kt0 -> next kt2
      long a1 = A8FRAG(1);
      GCHUNK8(a1, 1); DMA4F(1, 1);      // kt1 -> next kt3
    }
  }
}

extern "C" void kernel_launch(void* const* d_in, const int* in_sizes, int n_in,
                              void* d_out, int out_size, void* d_ws, size_t ws_size,
                              hipStream_t stream) {
  const float* x       = (const float*)d_in[0];
  const float* w_ih    = (const float*)d_in[1];
  const float* w_hh    = (const float*)d_in[2];
  const float* b_ih    = (const float*)d_in[3];
  const float* b_hh    = (const float*)d_in[4];
  const float* pit_w1  = (const float*)d_in[5];
  const float* pit_b1  = (const float*)d_in[6];
  const float* pit_w2  = (const float*)d_in[7];
  const float* pit_b2  = (const float*)d_in[8];
  const float* time_w1 = (const float*)d_in[9];
  const float* time_b1 = (const float*)d_in[10];
  const float* time_w2 = (const float*)d_in[11];
  const float* time_b2 = (const float*)d_in[12];
  const float* ar_w1   = (const float*)d_in[13];
  const float* ar_b1   = (const float*)d_in[14];
  const float* ar_w2   = (const float*)d_in[15];
  const float* ar_b2   = (const float*)d_in[16];
  unsigned char* ws8   = (unsigned char*)d_ws;
  float* out           = (float*)d_out;

  prep_kernel<<<dim3((PREP_N + 255) / 256), dim3(256), 0, stream>>>(
      w_ih, w_hh, pit_w1, time_w1, ar_w1, ar_w2, ws8);
  rnn_kernel<<<dim3(16), dim3(NT), 0, stream>>>(
      x, b_ih, b_hh, pit_b1, pit_w2, pit_b2,
      time_w1, time_b1, time_w2, time_b2,
      ar_w1, ar_b1, ar_b2, ws8, out);
}